// Round 2
// baseline (848.430 us; speedup 1.0000x reference)
//
#include <hip/hip_runtime.h>
#include <hip/hip_bf16.h>

typedef unsigned int u32;
typedef unsigned short u16;
typedef short short8 __attribute__((ext_vector_type(8)));
typedef float f32x4 __attribute__((ext_vector_type(4)));

#define R_ 32
#define KEYS_PER_B 2048   // 32 relations * 64 nodes per batch
#define SSTAGE 896        // staged sorted-edge slots per block (avg 767, +4.6 sigma; overflow falls back to global)
#define EBUF 8            // per-wave buffered edge loads kept in flight under the GEMM

static __device__ __forceinline__ u16 f2bf(float f) {
  u32 u = __float_as_uint(f);
  u = (u + 0x7FFFu + ((u >> 16) & 1u)) >> 16;   // RNE
  return (u16)u;
}
static __device__ __forceinline__ u32 pk2(float a, float b) {
  __hip_bfloat162 h2 = __float22bfloat162_rn(make_float2(a, b));
  union { __hip_bfloat162 h; u32 u; } cv; cv.h = h2; return cv.u;
}

// ---- x fp32 -> bf16 ----
__global__ void k_convert_x(const float* __restrict__ x, u16* __restrict__ xb, int n4) {
  int i = blockIdx.x * 256 + threadIdx.x;
  if (i >= n4) return;
  const float4 f = ((const float4*)x)[i];
  u32 lo = (u32)f2bf(f.x) | ((u32)f2bf(f.y) << 16);
  u32 hi = (u32)f2bf(f.z) | ((u32)f2bf(f.w) << 16);
  ((uint2*)xb)[i] = make_uint2(lo, hi);
}

// ---- pack W (and W_root as slot 32) into MFMA B-fragment order ----
__global__ void k_pack_w(const float* __restrict__ W, const float* __restrict__ Wroot,
                         u16* __restrict__ wp, u16* __restrict__ wrootp) {
  int tid = blockIdx.x * 256 + threadIdx.x;
  if (tid >= 33 * 2048) return;
  int lane = tid & 63;
  int ks = (tid >> 6) & 3;
  int ct = (tid >> 8) & 7;
  int rr = tid >> 11;
  int i0 = ks * 32 + (lane >> 4) * 8;
  int o  = ct * 16 + (lane & 15);
  const float* src = (rr < 32) ? (W + (size_t)rr * (128 * 128)) : Wroot;
  u16* dst = (rr < 32) ? (wp + ((size_t)((rr * 8 + ct) * 4 + ks) * 64 + lane) * 8)
                       : (wrootp + ((size_t)((ct * 4 + ks) * 64 + lane)) * 8);
#pragma unroll
  for (int j = 0; j < 8; ++j) dst[j] = f2bf(src[(size_t)(i0 + j) * 128 + o]);
}

// ---- histogram of sort keys ----
__global__ void k_hist(const int* __restrict__ ei, const int* __restrict__ et,
                       int* __restrict__ hist, int E) {
  int e = blockIdx.x * 256 + threadIdx.x;
  if (e >= E) return;
  int tgt = ei[E + e];
  int r = et[e];
  int key = (tgt >> 6) * KEYS_PER_B + r * 64 + (tgt & 63);
  atomicAdd(hist + key, 1);
}

// ---- per-chunk exclusive scan (chunk = 2048 keys = one batch) ----
__global__ __launch_bounds__(256) void k_scan_local(const int* __restrict__ hist,
                                                    int* __restrict__ offs,
                                                    int* __restrict__ chunkSums) {
  __shared__ int wsum[4];
  int b = blockIdx.x, t = threadIdx.x;
  size_t base = (size_t)b * KEYS_PER_B + (size_t)t * 8;
  int4 a = *(const int4*)(hist + base);
  int4 c = *(const int4*)(hist + base + 4);
  int v[8] = {a.x, a.y, a.z, a.w, c.x, c.y, c.z, c.w};
  int s = 0;
#pragma unroll
  for (int i = 0; i < 8; ++i) s += v[i];
  int lane = t & 63, w = t >> 6;
  int x = s;
#pragma unroll
  for (int off = 1; off < 64; off <<= 1) {
    int y = __shfl_up(x, off);
    if (lane >= off) x += y;
  }
  if (lane == 63) wsum[w] = x;
  __syncthreads();
  int wb = 0;
  for (int i = 0; i < w; ++i) wb += wsum[i];
  int ex = wb + x - s;
  int o[8];
#pragma unroll
  for (int i = 0; i < 8; ++i) { o[i] = ex; ex += v[i]; }
  *(int4*)(offs + base) = make_int4(o[0], o[1], o[2], o[3]);
  *(int4*)(offs + base + 4) = make_int4(o[4], o[5], o[6], o[7]);
  if (t == 255) chunkSums[b] = wb + x;
}

// ---- scan of chunk sums (1 block, 1 wave) ----
__global__ void k_scan_chunks(const int* __restrict__ cs, int* __restrict__ cb, int n) {
  int l = threadIdx.x;
  int carry = 0;
  int iters = (n + 63) >> 6;
  for (int i = 0; i < iters; ++i) {
    int idx = i * 64 + l;
    int v = (idx < n) ? cs[idx] : 0;
    int x = v;
#pragma unroll
    for (int off = 1; off < 64; off <<= 1) {
      int y = __shfl_up(x, off);
      if (l >= off) x += y;
    }
    if (idx < n) cb[idx] = carry + x - v;
    carry += __shfl(x, 63);
  }
}

// ---- scatter to sorted order; sorted[] = src | tgtLocal<<16 (N < 65536) ----
__global__ void k_scatter(const int* __restrict__ ei, const int* __restrict__ et,
                          int* __restrict__ offs, const int* __restrict__ chunkBase,
                          u32* __restrict__ sorted, int E) {
  int e = blockIdx.x * 256 + threadIdx.x;
  if (e >= E) return;
  int src = ei[e];
  int tgt = ei[E + e];
  int r = et[e];
  int chunk = tgt >> 6;
  int key = chunk * KEYS_PER_B + r * 64 + (tgt & 63);
  int p = atomicAdd(offs + key, 1) + chunkBase[chunk];
  sorted[p] = (u32)src | ((u32)(tgt & 63) << 16);
}

// ---- main batch kernel ----
// Per relation r, software-pipelined:
//   phase B: pack aggf(fp32,swizzled) -> aggb(bf16, MFMA A layout), rezero aggf
//   phase A: GEMM(r) overlapped with buffered edge gather+ds_add for r+1
// aggf layout: col c lives at slot (c>>1)+(c&1)*64, XOR'd by 4*(row&7) -> all
// ds_add_f32 are 2-way bank aliased (free), pack b128 reads hit min 8/start.
__global__ __launch_bounds__(256) void k_batch(
    const u16* __restrict__ xb, const u16* __restrict__ wp, const u16* __restrict__ wrootp,
    const float* __restrict__ bias, const u32* __restrict__ sorted,
    const int* __restrict__ offs, const int* __restrict__ hist,
    const int* __restrict__ chunkBase, float* __restrict__ h, int N) {
  __shared__ float aggf[64 * 128];   // 32 KB
  __shared__ u16 aggb[64 * 136];     // 17 KB
  __shared__ u32 sStage[SSTAGE];     // 3.5 KB
  const int b = blockIdx.x, t = threadIdx.x;
  const int lane = t & 63, w = t >> 6;
  const int m = lane & 15, q = lane >> 4;
  const int nb = b * 64;
  const int keyBase = b * KEYS_PER_B;
  const int cb = chunkBase[b];
  const int prow = t >> 2, pcg = t & 3;      // pack-phase assignment
  const int pX = 4 * (prow & 7);

  // ---- init: zero aggf, stage sorted edges, root GEMM ----
#pragma unroll
  for (int k = 0; k < 8; ++k)
    *(f32x4*)(aggf + t * 32 + k * 4) = (f32x4){0.f, 0.f, 0.f, 0.f};
  const int nEdge = offs[keyBase + KEYS_PER_B - 1];
  for (int i = t; i < nEdge && i < SSTAGE; i += 256) sStage[i] = sorted[cb + i];

  int cntCur = hist[keyBase + prow];   // cnt for (relation 0, row prow)

  const short8 zero8 = {0, 0, 0, 0, 0, 0, 0, 0};
  f32x4 acc[4][2];
#pragma unroll
  for (int rt = 0; rt < 4; ++rt)
#pragma unroll
    for (int c = 0; c < 2; ++c) acc[rt][c] = (f32x4){0.f, 0.f, 0.f, 0.f};
  const int wct0 = w * 2;

  // root GEMM: acc += x_batch @ W_root (global reads only, overlaps staging)
#pragma unroll
  for (int ks = 0; ks < 4; ++ks) {
    const int kb = ks * 32 + q * 8;
    short8 af[4];
#pragma unroll
    for (int rt = 0; rt < 4; ++rt) {
      int node = nb + rt * 16 + m;
      af[rt] = (node < N) ? *(const short8*)(xb + (size_t)node * 128 + kb) : zero8;
    }
#pragma unroll
    for (int c = 0; c < 2; ++c) {
      short8 bf = *(const short8*)(wrootp + ((size_t)(((wct0 + c) * 4 + ks) * 64 + lane)) * 8);
#pragma unroll
      for (int rt = 0; rt < 4; ++rt)
        acc[rt][c] = __builtin_amdgcn_mfma_f32_16x16x32_bf16(af[rt], bf, acc[rt][c], 0, 0, 0);
    }
  }

  // bounds for relation 0
  int k1 = keyBase;
  int sA = offs[k1] - hist[k1];
  int sB = offs[k1 + 63];

  __syncthreads();   // aggf zeroed + sStage ready

  // scatter helper (buffered; positions base+4j belong to this wave)
  auto scatter = [&](int s0, int s1) {
    const int base = s0 + w;
    const int nW = (s1 > base) ? ((s1 - base + 3) >> 2) : 0;
    const int nB = nW < EBUF ? nW : EBUF;
    u32 xv[EBUF]; int tb[EBUF];
#pragma unroll
    for (int j = 0; j < EBUF; ++j) {
      if (j < nB) {
        int p = base + 4 * j;
        u32 e = (p < SSTAGE) ? sStage[p] : sorted[cb + p];
        tb[j] = (e >> 16) & 63;
        xv[j] = *(const u32*)(xb + (size_t)(e & 0xFFFFu) * 128 + 2 * lane);
      }
    }
#pragma unroll
    for (int j = 0; j < EBUF; ++j) {
      if (j < nB) {
        int tl = tb[j];
        int o = lane ^ (4 * (tl & 7));
        float* rp = aggf + tl * 128;
        atomicAdd(rp + o, __uint_as_float(xv[j] << 16));
        atomicAdd(rp + o + 64, __uint_as_float(xv[j] & 0xFFFF0000u));
      }
    }
    for (int p = base + 4 * EBUF; p < s1; p += 4) {   // rare overflow
      u32 e = (p < SSTAGE) ? sStage[p] : sorted[cb + p];
      int tl = (e >> 16) & 63;
      u32 x = *(const u32*)(xb + (size_t)(e & 0xFFFFu) * 128 + 2 * lane);
      int o = lane ^ (4 * (tl & 7));
      float* rp = aggf + tl * 128;
      atomicAdd(rp + o, __uint_as_float(x << 16));
      atomicAdd(rp + o + 64, __uint_as_float(x & 0xFFFF0000u));
    }
  };

  // scatter relation 0 (nothing to overlap yet)
  scatter(sA, sB);
  __syncthreads();

  // ---- pipelined relation loop ----
  for (int r = 0; r < R_; ++r) {
    // prefetch bounds for relation r+1 (used in phase A)
    int s0n = 0, s1n = 0;
    if (r < 31) {
      int kk1 = keyBase + (r + 1) * 64;
      s0n = offs[kk1] - hist[kk1];
      s1n = offs[kk1 + 63];
    }
    // ---- phase B: pack relation r: aggf -> aggb (bf16), rezero aggf ----
    {
      const float sc = 1.0f / (float)(cntCur > 0 ? cntCur : 1);
      float* rp = aggf + prow * 128;
      u32* ab = (u32*)aggb + prow * 68 + pcg * 16;
#pragma unroll
      for (int k = 0; k < 4; ++k) {
        const int se = (pcg * 16 + k * 4) ^ pX;
        f32x4 ev = *(f32x4*)(rp + se);
        f32x4 od = *(f32x4*)(rp + se + 64);
        *(f32x4*)(rp + se) = (f32x4){0.f, 0.f, 0.f, 0.f};
        *(f32x4*)(rp + se + 64) = (f32x4){0.f, 0.f, 0.f, 0.f};
        uint4 o;
        o.x = pk2(ev[0] * sc, od[0] * sc);
        o.y = pk2(ev[1] * sc, od[1] * sc);
        o.z = pk2(ev[2] * sc, od[2] * sc);
        o.w = pk2(ev[3] * sc, od[3] * sc);
        *(uint4*)(ab + k * 4) = o;
      }
    }
    __syncthreads();

    // ---- phase A: GEMM(r) + buffered scatter(r+1) + cnt prefetch ----
    if (r < 31) cntCur = hist[keyBase + (r + 1) * 64 + prow];
    // B fragments first (global, L2-resident)
    short8 bfr[4][2];
#pragma unroll
    for (int ks = 0; ks < 4; ++ks)
#pragma unroll
      for (int c = 0; c < 2; ++c)
        bfr[ks][c] = *(const short8*)(wp + ((size_t)(((r * 8 + wct0 + c) * 4 + ks) * 64 + lane)) * 8);

    if (r < 31) {
      // issue edge buffer loads, then GEMM under their latency, then drain
      const int base = s0n + w;
      const int nW = (s1n > base) ? ((s1n - base + 3) >> 2) : 0;
      const int nB = nW < EBUF ? nW : EBUF;
      u32 xv[EBUF]; int tb[EBUF];
#pragma unroll
      for (int j = 0; j < EBUF; ++j) {
        if (j < nB) {
          int p = base + 4 * j;
          u32 e = (p < SSTAGE) ? sStage[p] : sorted[cb + p];
          tb[j] = (e >> 16) & 63;
          xv[j] = *(const u32*)(xb + (size_t)(e & 0xFFFFu) * 128 + 2 * lane);
        }
      }
      // GEMM
#pragma unroll
      for (int ks = 0; ks < 4; ++ks) {
        const int kb = ks * 32 + q * 8;
        short8 af[4];
#pragma unroll
        for (int rt = 0; rt < 4; ++rt)
          af[rt] = *(const short8*)(aggb + (size_t)(rt * 16 + m) * 136 + kb);
#pragma unroll
        for (int c = 0; c < 2; ++c)
#pragma unroll
          for (int rt = 0; rt < 4; ++rt)
            acc[rt][c] = __builtin_amdgcn_mfma_f32_16x16x32_bf16(af[rt], bfr[ks][c], acc[rt][c], 0, 0, 0);
      }
      // drain ds_adds
#pragma unroll
      for (int j = 0; j < EBUF; ++j) {
        if (j < nB) {
          int tl = tb[j];
          int o = lane ^ (4 * (tl & 7));
          float* rp = aggf + tl * 128;
          atomicAdd(rp + o, __uint_as_float(xv[j] << 16));
          atomicAdd(rp + o + 64, __uint_as_float(xv[j] & 0xFFFF0000u));
        }
      }
      for (int p = base + 4 * EBUF; p < s1n; p += 4) {
        u32 e = (p < SSTAGE) ? sStage[p] : sorted[cb + p];
        int tl = (e >> 16) & 63;
        u32 x = *(const u32*)(xb + (size_t)(e & 0xFFFFu) * 128 + 2 * lane);
        int o = lane ^ (4 * (tl & 7));
        float* rp = aggf + tl * 128;
        atomicAdd(rp + o, __uint_as_float(x << 16));
        atomicAdd(rp + o + 64, __uint_as_float(x & 0xFFFF0000u));
      }
    } else {
      // last relation: GEMM only
#pragma unroll
      for (int ks = 0; ks < 4; ++ks) {
        const int kb = ks * 32 + q * 8;
        short8 af[4];
#pragma unroll
        for (int rt = 0; rt < 4; ++rt)
          af[rt] = *(const short8*)(aggb + (size_t)(rt * 16 + m) * 136 + kb);
#pragma unroll
        for (int c = 0; c < 2; ++c)
#pragma unroll
          for (int rt = 0; rt < 4; ++rt)
            acc[rt][c] = __builtin_amdgcn_mfma_f32_16x16x32_bf16(af[rt], bfr[ks][c], acc[rt][c], 0, 0, 0);
      }
    }
    __syncthreads();
  }

  // ---- epilogue: bias + relu + store h (fp32) ----
#pragma unroll
  for (int c = 0; c < 2; ++c) {
    const int col = (wct0 + c) * 16 + m;
    const float bv = bias[col];
#pragma unroll
    for (int rt = 0; rt < 4; ++rt) {
#pragma unroll
      for (int g = 0; g < 4; ++g) {
        const int row = nb + rt * 16 + q * 4 + g;
        if (row < N) {
          float v = acc[rt][c][g] + bv;
          h[(size_t)row * 128 + col] = v > 0.f ? v : 0.f;
        }
      }
    }
  }
}

// ---- DistMult scoring: one wave per triplet ----
__global__ void k_score(const float* __restrict__ h, const float* __restrict__ rel_emb,
                        const int* __restrict__ head, const int* __restrict__ tail,
                        const int* __restrict__ rel, float* __restrict__ out, int T) {
  int lane = threadIdx.x & 63, w = threadIdx.x >> 6;
  int gid = blockIdx.x * 4 + w;
  if (gid >= T) return;
  const float* ph = h + (size_t)head[gid] * 128;
  const float* pt = h + (size_t)tail[gid] * 128;
  const float* pr = rel_emb + (size_t)rel[gid] * 128;
  float s = ph[lane] * pr[lane] * pt[lane] + ph[lane + 64] * pr[lane + 64] * pt[lane + 64];
#pragma unroll
  for (int off = 32; off > 0; off >>= 1) s += __shfl_down(s, off);
  if (lane == 0) out[gid] = s;
}

extern "C" void kernel_launch(void* const* d_in, const int* in_sizes, int n_in,
                              void* d_out, int out_size, void* d_ws, size_t ws_size,
                              hipStream_t stream) {
  const float* x     = (const float*)d_in[0];
  const float* W     = (const float*)d_in[1];
  const float* Wroot = (const float*)d_in[2];
  const float* bias  = (const float*)d_in[3];
  const float* relE  = (const float*)d_in[4];
  const int* ei      = (const int*)d_in[5];
  const int* et      = (const int*)d_in[6];
  const int* headI   = (const int*)d_in[7];
  const int* tailI   = (const int*)d_in[8];
  const int* relI    = (const int*)d_in[9];
  float* out = (float*)d_out;

  const int N = in_sizes[0] / 128;   // 50000
  const int E = in_sizes[6];         // 600000
  const int T = in_sizes[7];         // 8192
  const int NB = (N + 63) >> 6;      // 782
  const int NKEYS = NB * KEYS_PER_B;

  char* p = (char*)d_ws;
  auto alloc = [&](size_t bytes) -> void* {
    void* r = (void*)p;
    p += (bytes + 255) & ~(size_t)255;
    return r;
  };
  u16* xb     = (u16*)alloc((size_t)N * 128 * 2);
  u16* wp     = (u16*)alloc((size_t)32 * 2048 * 8 * 2);
  u16* wrootp = (u16*)alloc((size_t)2048 * 8 * 2);
  int* hist   = (int*)alloc((size_t)NKEYS * 4);
  int* offs   = (int*)alloc((size_t)NKEYS * 4);
  int* csum   = (int*)alloc((size_t)NB * 4);
  int* cbase  = (int*)alloc((size_t)NB * 4);
  u32* sorted = (u32*)alloc((size_t)E * 4);
  float* h    = (float*)alloc((size_t)N * 128 * 4);

  hipMemsetAsync(hist, 0, (size_t)NKEYS * 4, stream);
  k_convert_x<<<(N * 128 / 4 + 255) / 256, 256, 0, stream>>>(x, xb, N * 128 / 4);
  k_pack_w<<<(33 * 2048 + 255) / 256, 256, 0, stream>>>(W, Wroot, wp, wrootp);
  k_hist<<<(E + 255) / 256, 256, 0, stream>>>(ei, et, hist, E);
  k_scan_local<<<NB, 256, 0, stream>>>(hist, offs, csum);
  k_scan_chunks<<<1, 64, 0, stream>>>(csum, cbase, NB);
  k_scatter<<<(E + 255) / 256, 256, 0, stream>>>(ei, et, offs, cbase, sorted, E);
  k_batch<<<NB, 256, 0, stream>>>(xb, wp, wrootp, bias, sorted, offs, hist, cbase, h, N);
  k_score<<<(T + 3) / 4, 256, 0, stream>>>(h, relE, headI, tailI, relI, out, T);
}

// Round 3
// 331.866 us; speedup vs baseline: 2.5565x; 2.5565x over previous
//
#include <hip/hip_runtime.h>
#include <hip/hip_bf16.h>

typedef unsigned int u32;
typedef unsigned short u16;
typedef short short8 __attribute__((ext_vector_type(8)));
typedef float f32x4 __attribute__((ext_vector_type(4)));

#define R_ 32
#define KEYS_PER_B 2048     // 4 wavegroups * 32 relations * 16 rows
#define SORT_STRIDE 1024    // fixed per-chunk slots in sorted[] (mean 767, +9 sigma)
#define CAP 16              // per-wave per-relation buffered edge gathers

static __device__ __forceinline__ u16 f2bf(float f) {
  u32 u = __float_as_uint(f);
  u = (u + 0x7FFFu + ((u >> 16) & 1u)) >> 16;   // RNE
  return (u16)u;
}
static __device__ __forceinline__ u32 pk2(float a, float b) {
  __hip_bfloat162 h2 = __float22bfloat162_rn(make_float2(a, b));
  union { __hip_bfloat162 h; u32 u; } cv; cv.h = h2; return cv.u;
}

// ---- fused: x fp32->bf16 convert  +  W/W_root pack into MFMA B-fragment order ----
__global__ void k_pre(const float* __restrict__ x, const float* __restrict__ W,
                      const float* __restrict__ Wroot, u16* __restrict__ xb,
                      u16* __restrict__ wp, u16* __restrict__ wrootp,
                      int n4, int convNB) {
  if ((int)blockIdx.x < convNB) {
    int i = blockIdx.x * 256 + threadIdx.x;
    if (i >= n4) return;
    const float4 f = ((const float4*)x)[i];
    u32 lo = (u32)f2bf(f.x) | ((u32)f2bf(f.y) << 16);
    u32 hi = (u32)f2bf(f.z) | ((u32)f2bf(f.w) << 16);
    ((uint2*)xb)[i] = make_uint2(lo, hi);
  } else {
    int tid = (blockIdx.x - convNB) * 256 + threadIdx.x;
    if (tid >= 33 * 2048) return;
    int lane = tid & 63;
    int ks = (tid >> 6) & 3;
    int ct = (tid >> 8) & 7;
    int rr = tid >> 11;
    int i0 = ks * 32 + (lane >> 4) * 8;
    int o  = ct * 16 + (lane & 15);
    const float* src = (rr < 32) ? (W + (size_t)rr * (128 * 128)) : Wroot;
    u16* dst = (rr < 32) ? (wp + ((size_t)((rr * 8 + ct) * 4 + ks) * 64 + lane) * 8)
                         : (wrootp + ((size_t)((ct * 4 + ks) * 64 + lane)) * 8);
#pragma unroll
    for (int j = 0; j < 8; ++j) dst[j] = f2bf(src[(size_t)(i0 + j) * 128 + o]);
  }
}

static __device__ __forceinline__ int sort_key(int tgt, int r) {
  return (tgt >> 6) * KEYS_PER_B + ((tgt >> 4) & 3) * 512 + r * 16 + (tgt & 15);
}

// ---- histogram of sort keys ----
__global__ void k_hist(const int* __restrict__ ei, const int* __restrict__ et,
                       int* __restrict__ hist, int E) {
  int e = blockIdx.x * 256 + threadIdx.x;
  if (e >= E) return;
  atomicAdd(hist + sort_key(ei[E + e], et[e]), 1);
}

// ---- per-chunk exclusive scan (chunk = 2048 keys = one batch) ----
__global__ __launch_bounds__(256) void k_scan_local(const int* __restrict__ hist,
                                                    int* __restrict__ offs) {
  __shared__ int wsum[4];
  int b = blockIdx.x, t = threadIdx.x;
  size_t base = (size_t)b * KEYS_PER_B + (size_t)t * 8;
  int4 a = *(const int4*)(hist + base);
  int4 c = *(const int4*)(hist + base + 4);
  int v[8] = {a.x, a.y, a.z, a.w, c.x, c.y, c.z, c.w};
  int s = 0;
#pragma unroll
  for (int i = 0; i < 8; ++i) s += v[i];
  int lane = t & 63, w = t >> 6;
  int x = s;
#pragma unroll
  for (int off = 1; off < 64; off <<= 1) {
    int y = __shfl_up(x, off);
    if (lane >= off) x += y;
  }
  if (lane == 63) wsum[w] = x;
  __syncthreads();
  int wb = 0;
  for (int i = 0; i < w; ++i) wb += wsum[i];
  int ex = wb + x - s;
  int o[8];
#pragma unroll
  for (int i = 0; i < 8; ++i) { o[i] = ex; ex += v[i]; }
  *(int4*)(offs + base) = make_int4(o[0], o[1], o[2], o[3]);
  *(int4*)(offs + base + 4) = make_int4(o[4], o[5], o[6], o[7]);
}

// ---- scatter; offs[key] becomes per-key chunk-local END; sorted = src | row64<<16 ----
__global__ void k_scatter(const int* __restrict__ ei, const int* __restrict__ et,
                          int* __restrict__ offs, u32* __restrict__ sorted, int E) {
  int e = blockIdx.x * 256 + threadIdx.x;
  if (e >= E) return;
  int src = ei[e];
  int tgt = ei[E + e];
  int r = et[e];
  int p = atomicAdd(offs + sort_key(tgt, r), 1);
  if (p < SORT_STRIDE)
    sorted[(size_t)(tgt >> 6) * SORT_STRIDE + p] = (u32)src | ((u32)(tgt & 63) << 16);
}

// ---- main batch kernel ----
// Wave w owns rows w*16..w*16+15. Its edges for relation r are CONTIGUOUS in
// sorted (key = batch,wavegroup,rel,row). Per relation:
//   build(r): zero own aggb rows; consume prefetched xv[] with run-detection
//             (rows sorted -> one flush per non-empty row; mean = run length)
//   barrier
//   phaseA(r): issue ev+xv gathers for r+1 (16-deep, in flight across GEMM),
//              prefetch offs end for r+2, GEMM(r) from aggb + wp
//   barrier
__global__ __launch_bounds__(256) void k_batch(
    const u16* __restrict__ xb, const u16* __restrict__ wp, const u16* __restrict__ wrootp,
    const float* __restrict__ bias, const u32* __restrict__ sorted,
    const int* __restrict__ offs, float* __restrict__ h, int N) {
  __shared__ u16 aggb[64 * 136];   // 17.4 KB
  const int b = blockIdx.x, t = threadIdx.x;
  const int lane = t & 63, w = t >> 6;
  const int m = lane & 15, q = lane >> 4;
  const int nb = b * 64;
  const int keyBase = b * KEYS_PER_B;
  const int wkBase = keyBase + w * 512;
  const u32* srt = sorted + (size_t)b * SORT_STRIDE;

  const int nEdge = offs[keyBase + KEYS_PER_B - 1];
  const int clampP = (nEdge > 0) ? nEdge - 1 : 0;
  int sCur = (w == 0) ? 0 : offs[wkBase - 1];   // start of relation 0 (chunk-local)
  int eCur = offs[wkBase + 15];                 // end of relation 0
  int eNext = offs[wkBase + 31];                // end of relation 1

  // prologue: issue gathers for relation 0 (overlap root GEMM)
  u32 ev;
  {
    int pc = sCur + m;
    if (pc > clampP) pc = clampP;
    ev = srt[pc];
  }
  u32 xv[CAP];
  {
    const int nB = min(eCur - sCur, CAP);
#pragma unroll
    for (int j = 0; j < CAP; ++j) {
      if (j < nB) {
        int e = __builtin_amdgcn_readlane((int)ev, j);
        xv[j] = *(const u32*)(xb + (size_t)(e & 0xFFFF) * 128 + 2 * lane);
      }
    }
  }

  const short8 zero8 = {0, 0, 0, 0, 0, 0, 0, 0};
  f32x4 acc[4][2];
#pragma unroll
  for (int rt = 0; rt < 4; ++rt)
#pragma unroll
    for (int c = 0; c < 2; ++c) acc[rt][c] = (f32x4){0.f, 0.f, 0.f, 0.f};
  const int wct0 = w * 2;

  // root GEMM: acc += x_batch @ W_root
#pragma unroll
  for (int ks = 0; ks < 4; ++ks) {
    const int kb = ks * 32 + q * 8;
    short8 af[4];
#pragma unroll
    for (int rt = 0; rt < 4; ++rt) {
      int node = nb + rt * 16 + m;
      af[rt] = (node < N) ? *(const short8*)(xb + (size_t)node * 128 + kb) : zero8;
    }
#pragma unroll
    for (int c = 0; c < 2; ++c) {
      short8 bf = *(const short8*)(wrootp + ((size_t)(((wct0 + c) * 4 + ks) * 64 + lane)) * 8);
#pragma unroll
      for (int rt = 0; rt < 4; ++rt)
        acc[rt][c] = __builtin_amdgcn_mfma_f32_16x16x32_bf16(af[rt], bf, acc[rt][c], 0, 0, 0);
    }
  }
  __syncthreads();

  for (int r = 0; r < R_; ++r) {
    // ---- build(r): zero own rows, consume buffer with run detection ----
#pragma unroll
    for (int rr = 0; rr < 16; ++rr)
      *(u32*)(aggb + (size_t)(w * 16 + rr) * 136 + 2 * lane) = 0;

    {
      const int nB = min(eCur - sCur, CAP);
      int curRow = -1, rc = 0;
      float v0 = 0.f, v1 = 0.f;
#pragma unroll
      for (int j = 0; j < CAP; ++j) {
        if (j < nB) {
          int e = __builtin_amdgcn_readlane((int)ev, j);
          int tl = (e >> 16) & 63;
          if (tl != curRow) {
            if (rc > 0) {
              float sc = 1.0f / (float)rc;
              *(u32*)(aggb + (size_t)curRow * 136 + 2 * lane) = pk2(v0 * sc, v1 * sc);
            }
            curRow = tl; v0 = 0.f; v1 = 0.f; rc = 0;
          }
          v0 += __uint_as_float(xv[j] << 16);
          v1 += __uint_as_float(xv[j] & 0xFFFF0000u);
          ++rc;
        }
      }
      // rare overflow tail (cnt > CAP): serial loads
      for (int p = sCur + CAP; p < eCur; ++p) {
        u32 e = srt[p];
        u32 xvv = *(const u32*)(xb + (size_t)(e & 0xFFFFu) * 128 + 2 * lane);
        int tl = (int)((e >> 16) & 63);
        if (tl != curRow) {
          if (rc > 0) {
            float sc = 1.0f / (float)rc;
            *(u32*)(aggb + (size_t)curRow * 136 + 2 * lane) = pk2(v0 * sc, v1 * sc);
          }
          curRow = tl; v0 = 0.f; v1 = 0.f; rc = 0;
        }
        v0 += __uint_as_float(xvv << 16);
        v1 += __uint_as_float(xvv & 0xFFFF0000u);
        ++rc;
      }
      if (rc > 0) {
        float sc = 1.0f / (float)rc;
        *(u32*)(aggb + (size_t)curRow * 136 + 2 * lane) = pk2(v0 * sc, v1 * sc);
      }
    }
    __syncthreads();

    // ---- phase A: issue gathers for r+1, prefetch bounds for r+2, GEMM(r) ----
    if (r < R_ - 1) {
      const int sN = eCur;
      const int eN = eNext;
      int pc = sN + m;
      if (pc > clampP) pc = clampP;
      ev = srt[pc];
      const int nBn = min(eN - sN, CAP);
#pragma unroll
      for (int j = 0; j < CAP; ++j) {
        if (j < nBn) {
          int e = __builtin_amdgcn_readlane((int)ev, j);
          xv[j] = *(const u32*)(xb + (size_t)(e & 0xFFFF) * 128 + 2 * lane);
        }
      }
      if (r < R_ - 2) eNext = offs[wkBase + (r + 2) * 16 + 15];
      sCur = sN; eCur = eN;
    }

    // GEMM(r): acc += agg @ W[r]
    short8 bfr[4][2];
#pragma unroll
    for (int ks = 0; ks < 4; ++ks)
#pragma unroll
      for (int c = 0; c < 2; ++c)
        bfr[ks][c] = *(const short8*)(wp + ((size_t)(((r * 8 + wct0 + c) * 4 + ks) * 64 + lane)) * 8);
#pragma unroll
    for (int ks = 0; ks < 4; ++ks) {
      const int kb = ks * 32 + q * 8;
      short8 af[4];
#pragma unroll
      for (int rt = 0; rt < 4; ++rt)
        af[rt] = *(const short8*)(aggb + (size_t)(rt * 16 + m) * 136 + kb);
#pragma unroll
      for (int c = 0; c < 2; ++c)
#pragma unroll
        for (int rt = 0; rt < 4; ++rt)
          acc[rt][c] = __builtin_amdgcn_mfma_f32_16x16x32_bf16(af[rt], bfr[ks][c], acc[rt][c], 0, 0, 0);
    }
    __syncthreads();
  }

  // ---- epilogue: bias + relu + store h (fp32) ----
#pragma unroll
  for (int c = 0; c < 2; ++c) {
    const int col = (wct0 + c) * 16 + m;
    const float bv = bias[col];
#pragma unroll
    for (int rt = 0; rt < 4; ++rt) {
#pragma unroll
      for (int g = 0; g < 4; ++g) {
        const int row = nb + rt * 16 + q * 4 + g;
        if (row < N) {
          float v = acc[rt][c][g] + bv;
          h[(size_t)row * 128 + col] = v > 0.f ? v : 0.f;
        }
      }
    }
  }
}

// ---- DistMult scoring: one wave per triplet, float2 loads ----
__global__ void k_score(const float* __restrict__ h, const float* __restrict__ rel_emb,
                        const int* __restrict__ head, const int* __restrict__ tail,
                        const int* __restrict__ rel, float* __restrict__ out, int T) {
  int lane = threadIdx.x & 63, w = threadIdx.x >> 6;
  int gid = blockIdx.x * 4 + w;
  if (gid >= T) return;
  const float2 h2 = *(const float2*)(h + (size_t)head[gid] * 128 + 2 * lane);
  const float2 t2 = *(const float2*)(h + (size_t)tail[gid] * 128 + 2 * lane);
  const float2 r2 = *(const float2*)(rel_emb + (size_t)rel[gid] * 128 + 2 * lane);
  float s = h2.x * r2.x * t2.x + h2.y * r2.y * t2.y;
#pragma unroll
  for (int off = 32; off > 0; off >>= 1) s += __shfl_down(s, off);
  if (lane == 0) out[gid] = s;
}

extern "C" void kernel_launch(void* const* d_in, const int* in_sizes, int n_in,
                              void* d_out, int out_size, void* d_ws, size_t ws_size,
                              hipStream_t stream) {
  const float* x     = (const float*)d_in[0];
  const float* W     = (const float*)d_in[1];
  const float* Wroot = (const float*)d_in[2];
  const float* bias  = (const float*)d_in[3];
  const float* relE  = (const float*)d_in[4];
  const int* ei      = (const int*)d_in[5];
  const int* et      = (const int*)d_in[6];
  const int* headI   = (const int*)d_in[7];
  const int* tailI   = (const int*)d_in[8];
  const int* relI    = (const int*)d_in[9];
  float* out = (float*)d_out;

  const int N = in_sizes[0] / 128;   // 50000
  const int E = in_sizes[6];         // 600000
  const int T = in_sizes[7];         // 8192
  const int NB = (N + 63) >> 6;      // 782
  const int NKEYS = NB * KEYS_PER_B;

  char* p = (char*)d_ws;
  auto alloc = [&](size_t bytes) -> void* {
    void* r = (void*)p;
    p += (bytes + 255) & ~(size_t)255;
    return r;
  };
  u16* xb     = (u16*)alloc((size_t)N * 128 * 2);        // 12.8 MB
  u16* wp     = (u16*)alloc((size_t)32 * 2048 * 8 * 2);  // 1 MB
  u16* wrootp = (u16*)alloc((size_t)2048 * 8 * 2);
  int* hist   = (int*)alloc((size_t)NKEYS * 4);          // 6.4 MB
  int* offs   = (int*)alloc((size_t)NKEYS * 4);          // 6.4 MB
  u32* sorted = (u32*)alloc((size_t)NB * SORT_STRIDE * 4); // 3.2 MB
  float* h    = (float*)alloc((size_t)N * 128 * 4);      // 25.6 MB

  const int n4 = N * 128 / 4;
  const int convNB = (n4 + 255) / 256;
  const int packNB = (33 * 2048 + 255) / 256;

  hipMemsetAsync(hist, 0, (size_t)NKEYS * 4, stream);
  k_pre<<<convNB + packNB, 256, 0, stream>>>(x, W, Wroot, xb, wp, wrootp, n4, convNB);
  k_hist<<<(E + 255) / 256, 256, 0, stream>>>(ei, et, hist, E);
  k_scan_local<<<NB, 256, 0, stream>>>(hist, offs);
  k_scatter<<<(E + 255) / 256, 256, 0, stream>>>(ei, et, offs, sorted, E);
  k_batch<<<NB, 256, 0, stream>>>(xb, wp, wrootp, bias, sorted, offs, h, N);
  k_score<<<(T + 3) / 4, 256, 0, stream>>>(h, relE, headI, tailI, relI, out, T);
}